// Round 1
// baseline (175.887 us; speedup 1.0000x reference)
//
#include <hip/hip_runtime.h>

// SpaNn belief-propagation decoder, sparse reformulation.
// N=1024 vars x DV=4 edges = E=4096; M=512 checks x DC=8.
// var_of_edge[e] = e>>2 (static by construction). Only the check
// connectivity (w_odd_to_even = same_chk & ~eye, symmetric) must be
// extracted from the inputs at runtime.

#define En 4096
#define Nn 1024
#define Mn 512
#define EPSF 1.1920929e-07f

// ---------------------------------------------------------------------------
// Kernel 1: extract check->edge lists from w_odd_to_even (upper triangle).
// One wave per row. A row with exactly 7 nonzeros to its right is the
// minimum edge of its check; those 7 columns + itself = the check's 8 edges
// (ascending). Exactly 512 leader rows exist.
// ---------------------------------------------------------------------------
__global__ __launch_bounds__(256) void extract_checks(
    const float* __restrict__ w, int* __restrict__ counter,
    int* __restrict__ ce) {
  __shared__ int buf[4][8];
  const int lane = threadIdx.x & 63;
  const int wv   = threadIdx.x >> 6;
  const int row  = blockIdx.x * 4 + wv;
  const float4* rowp = (const float4*)(w + (size_t)row * En);

  int base = ((row + 1) >> 8) << 8;  // aligned 256-float chunk containing row+1
  int cnt  = 0;
  for (; base < En; base += 256) {
    float4 v = rowp[(base >> 2) + lane];
    int col  = base + lane * 4;
#pragma unroll
    for (int k = 0; k < 4; ++k) {
      float val = (k == 0) ? v.x : (k == 1) ? v.y : (k == 2) ? v.z : v.w;
      bool hit  = (val != 0.0f) && (col + k > row);
      unsigned long long m = __ballot(hit);
      if (hit) {
        int idx = cnt + __popcll(m & ((1ull << lane) - 1ull));
        if (idx < 8) buf[wv][idx] = col + k;
      }
      cnt += __popcll(m);
    }
  }
  __syncthreads();  // order LDS writes before lane-0 readback
  if (cnt == 7 && lane == 0) {
    int slot = atomicAdd(counter, 1);
    int* dst = ce + slot * 8;
    dst[0] = row;
#pragma unroll
    for (int k = 0; k < 7; ++k) dst[k + 1] = buf[wv][k];
  }
}

// ---------------------------------------------------------------------------
// Kernel 2: 5 BP iterations + output, single workgroup, all state in LDS.
// thread t (0..1023) = variable t, owning edges 4t..4t+3.
// threads 0..511 each own one check in the even phase.
// ---------------------------------------------------------------------------
__global__ __launch_bounds__(1024) void solve(
    const float* __restrict__ x, const int* __restrict__ ce_g,
    float* __restrict__ out) {
  __shared__ int   ce[Mn * 8];   // 16 KB
  __shared__ float ods[En];      // 16 KB  tanh(odd) messages
  __shared__ float evs[En];      // 16 KB  even messages
  const int t = threadIdx.x;

#pragma unroll
  for (int k = 0; k < 4; ++k) ce[t + k * 1024] = ce_g[t + k * 1024];

  const float xt = x[t];
  const float th0 = tanhf(0.5f * xt);  // llr_part[e] = x[var], same for 4 edges
#pragma unroll
  for (int k = 0; k < 4; ++k) ods[4 * t + k] = th0;
  __syncthreads();

  for (int it = 0; it < 5; ++it) {
    // --- even phase: per check, extrinsic product of tanh's -> 2*atanh ---
    if (t < Mn) {
      int e[8];
      float f[8];
#pragma unroll
      for (int k = 0; k < 8; ++k) e[k] = ce[t * 8 + k];
#pragma unroll
      for (int k = 0; k < 8; ++k) {
        float o = ods[e[k]];
        f[k] = (o == 0.0f) ? 1.0f : o;  // reference's zero->identity subst
      }
#pragma unroll
      for (int k = 0; k < 8; ++k) {
        float v = 1.0f;
#pragma unroll
        for (int j = 0; j < 8; ++j)
          if (j != k) v *= f[j];  // ascending order, matches np.prod
        if (v >= 1.0f)       v =  1.0f - EPSF;   // reference clamp semantics
        else if (v <= -1.0f) v = -1.0f + EPSF;
        evs[e[k]] = 2.0f * atanhf(v);
      }
    }
    __syncthreads();

    // --- odd phase (skipped after last even): per var, extrinsic sum ---
    if (it < 4) {
      float ev[4];
#pragma unroll
      for (int k = 0; k < 4; ++k) ev[k] = evs[4 * t + k];
#pragma unroll
      for (int k = 0; k < 4; ++k) {
        float s = 0.0f;
#pragma unroll
        for (int j = 0; j < 4; ++j)
          if (j != k) s += ev[j];  // ascending 3-term sum
        ods[4 * t + k] = tanhf(0.5f * (xt + s));
      }
      __syncthreads();
    }
  }

  // --- output: sigmoid(x + sum of final evens) ---
  float s4 = evs[4 * t] + evs[4 * t + 1] + evs[4 * t + 2] + evs[4 * t + 3];
  float z  = xt + s4;
  out[t]   = 1.0f / (1.0f + expf(-z));
}

// ---------------------------------------------------------------------------
extern "C" void kernel_launch(void* const* d_in, const int* in_sizes, int n_in,
                              void* d_out, int out_size, void* d_ws,
                              size_t ws_size, hipStream_t stream) {
  const float* x    = (const float*)d_in[0];  // [1024]
  const float* w_oe = (const float*)d_in[2];  // w_odd_to_even [4096,4096]
  float* out = (float*)d_out;

  int* counter = (int*)d_ws;
  int* ce      = (int*)((char*)d_ws + 256);  // 512*8 ints = 16 KB

  hipMemsetAsync(d_ws, 0, 256, stream);
  extract_checks<<<dim3(1024), dim3(256), 0, stream>>>(w_oe, counter, ce);
  solve<<<dim3(1), dim3(1024), 0, stream>>>(x, ce, out);
}

// Round 2
// 171.125 us; speedup vs baseline: 1.0278x; 1.0278x over previous
//
#include <hip/hip_runtime.h>

// SpaNn belief-propagation decoder, sparse reformulation (round 2).
// N=1024 vars x DV=4 edges = E=4096; M=512 checks x DC=8.
// var_of_edge[e] = e>>2 (static). Check connectivity is recovered from
// w_odd_to_even by reading ONLY each row's leftmost nonzero column f[e]:
// for a check with edges e1<e2<...<e8, f(e1)=e2 and f(ek>=2)=e1, so
//   key(e) = (f(f(e))==e && e<f(e)) ? e : f(e)
// maps every edge to its check's minimum edge. Expected read: ~8 MB.

#define En 4096
#define Nn 1024
#define Mn 512
#define EPSF 1.1920929e-07f

// ---------------------------------------------------------------------------
// Kernel 1: per row, find leftmost nonzero column. One wave per row,
// 1 KB chunks, ballot early-exit. Every row has exactly 7 nonzeros.
// ---------------------------------------------------------------------------
__global__ __launch_bounds__(256) void find_first_peer(
    const float* __restrict__ w, int* __restrict__ f) {
  const int lane = threadIdx.x & 63;
  const int wv   = threadIdx.x >> 6;
  const int row  = blockIdx.x * 4 + wv;
  const float4* rowp = (const float4*)(w + (size_t)row * En);

  for (int base = 0; base < En; base += 256) {
    float4 v = rowp[(base >> 2) + lane];
    bool any = (v.x != 0.0f) | (v.y != 0.0f) | (v.z != 0.0f) | (v.w != 0.0f);
    unsigned long long m = __ballot(any);
    if (m) {
      if (lane == __ffsll((unsigned long long)m) - 1) {
        int off = (v.x != 0.0f) ? 0 : (v.y != 0.0f) ? 1 : (v.z != 0.0f) ? 2 : 3;
        f[row] = base + 4 * lane + off;
      }
      break;
    }
  }
}

// ---------------------------------------------------------------------------
// Kernel 2: rebuild check lists from f[] in LDS, then 5 BP iterations +
// output. Single workgroup, 1024 threads; thread t = variable t (edges
// 4t..4t+3); threads <512 each own one check in the even phase.
// ---------------------------------------------------------------------------
__global__ __launch_bounds__(1024) void solve(
    const float* __restrict__ x, const int* __restrict__ f_g,
    float* __restrict__ out) {
  __shared__ int   fs[En];       // 16 KB  leftmost-peer
  __shared__ int   slotmap[En];  // 16 KB  min-edge -> check slot
  __shared__ int   ce[En];       // 16 KB  check -> 8 edges (ascending)
  __shared__ float ods[En];      // 16 KB  tanh(odd) messages
  __shared__ float evs[En];      // 16 KB  even messages
  __shared__ int   cnt[Mn];
  __shared__ int   nchk;
  const int t = threadIdx.x;

  // ---- preamble: build sorted check->edge lists ----
#pragma unroll
  for (int k = 0; k < 4; ++k) fs[t + k * 1024] = f_g[t + k * 1024];
  if (t < Mn) cnt[t] = 0;
  if (t == 0) nchk = 0;
  __syncthreads();

  int keys[4];
#pragma unroll
  for (int k = 0; k < 4; ++k) {
    int e   = 4 * t + k;
    int fe  = fs[e];
    int ffe = fs[fe];
    int key = (ffe == e && e < fe) ? e : fe;  // check's minimum edge
    keys[k] = key;
    if (key == e) slotmap[e] = atomicAdd(&nchk, 1);  // min edge claims a slot
  }
  __syncthreads();
#pragma unroll
  for (int k = 0; k < 4; ++k) {
    int e = 4 * t + k;
    int c = slotmap[keys[k]];
    int p = atomicAdd(&cnt[c], 1);
    ce[c * 8 + p] = e;  // unordered within check
  }
  __syncthreads();
  if (t < Mn) {  // restore ascending edge order (numerics depend on it)
    int v[8];
#pragma unroll
    for (int k = 0; k < 8; ++k) v[k] = ce[t * 8 + k];
    for (int i = 1; i < 8; ++i) {
      int key = v[i], j = i - 1;
      for (; j >= 0 && v[j] > key; --j) v[j + 1] = v[j];
      v[j + 1] = key;
    }
#pragma unroll
    for (int k = 0; k < 8; ++k) ce[t * 8 + k] = v[k];
  }

  // ---- BP iterations (bitwise-identical to reference ordering) ----
  const float xt  = x[t];
  const float th0 = tanhf(0.5f * xt);
#pragma unroll
  for (int k = 0; k < 4; ++k) ods[4 * t + k] = th0;
  __syncthreads();

  for (int it = 0; it < 5; ++it) {
    if (t < Mn) {
      int e[8];
      float f[8];
#pragma unroll
      for (int k = 0; k < 8; ++k) e[k] = ce[t * 8 + k];
#pragma unroll
      for (int k = 0; k < 8; ++k) {
        float o = ods[e[k]];
        f[k] = (o == 0.0f) ? 1.0f : o;  // reference's zero->identity subst
      }
#pragma unroll
      for (int k = 0; k < 8; ++k) {
        float v = 1.0f;
#pragma unroll
        for (int j = 0; j < 8; ++j)
          if (j != k) v *= f[j];  // ascending order, matches np.prod
        if (v >= 1.0f)       v =  1.0f - EPSF;
        else if (v <= -1.0f) v = -1.0f + EPSF;
        evs[e[k]] = 2.0f * atanhf(v);
      }
    }
    __syncthreads();

    if (it < 4) {
      float ev[4];
#pragma unroll
      for (int k = 0; k < 4; ++k) ev[k] = evs[4 * t + k];
#pragma unroll
      for (int k = 0; k < 4; ++k) {
        float s = 0.0f;
#pragma unroll
        for (int j = 0; j < 4; ++j)
          if (j != k) s += ev[j];  // ascending 3-term sum
        ods[4 * t + k] = tanhf(0.5f * (xt + s));
      }
      __syncthreads();
    }
  }

  // ---- output: sigmoid(x + sum of final evens) ----
  float s4 = evs[4 * t] + evs[4 * t + 1] + evs[4 * t + 2] + evs[4 * t + 3];
  float z  = xt + s4;
  out[t]   = 1.0f / (1.0f + expf(-z));
}

// ---------------------------------------------------------------------------
extern "C" void kernel_launch(void* const* d_in, const int* in_sizes, int n_in,
                              void* d_out, int out_size, void* d_ws,
                              size_t ws_size, hipStream_t stream) {
  const float* x    = (const float*)d_in[0];  // [1024]
  const float* w_oe = (const float*)d_in[2];  // w_odd_to_even [4096,4096]
  float* out = (float*)d_out;

  int* f = (int*)d_ws;  // [4096] leftmost peer per edge (every entry written)

  find_first_peer<<<dim3(1024), dim3(256), 0, stream>>>(w_oe, f);
  solve<<<dim3(1), dim3(1024), 0, stream>>>(x, f, out);
}